// Round 1
// baseline (544.631 us; speedup 1.0000x reference)
//
#include <hip/hip_runtime.h>

// db4 DWT, one level, symmetric padding, matching the JAX reference:
//   cA[t] = sum_m DEC_LO[m] * x_sym(2t+1-m),  t in [0, 8195)
//   cD[t] = sum_m DEC_HI[m] * x_sym(2t+1-m)
// x_sym(s) = x[-s-1] (s<0), x[s] (0<=s<N), x[2N-1-s] (s>=N)
// out layout per row: [cA (8195) | cD (8195)]

#define BB   4096
#define NN   16384
#define NOUT 8195          // floor((N + L - 1) / 2), L = 8
#define OUTROW (2 * NOUT)  // 16390

// LO_R[j] = DEC_LO[7-j], HI_R[j] = DEC_HI[7-j] so that
// cA = sum_j v[j]*LO_R[j] with v[j] = x_sym(2t-6+j)
__device__ __constant__ float LO_R[8] = {
     0.23037781330885523f,   //  DEC_LO[7]
     0.7148465705525415f,    //  DEC_LO[6]
     0.6308807679295904f,    //  DEC_LO[5]
    -0.02798376941698385f,   //  DEC_LO[4]
    -0.18703481171888114f,   //  DEC_LO[3]
     0.030841381835986965f,  //  DEC_LO[2]
     0.032883011666982945f,  //  DEC_LO[1]
    -0.010597401784997278f   //  DEC_LO[0]
};
__device__ __constant__ float HI_R[8] = {
    -0.010597401784997278f,  //  DEC_HI[7] =  DEC_LO[0]
    -0.032883011666982945f,  //  DEC_HI[6] = -DEC_LO[1]
     0.030841381835986965f,  //  DEC_HI[5] =  DEC_LO[2]
     0.18703481171888114f,   //  DEC_HI[4] = -DEC_LO[3]
    -0.02798376941698385f,   //  DEC_HI[3] =  DEC_LO[4]
    -0.6308807679295904f,    //  DEC_HI[2] = -DEC_LO[5]
     0.7148465705525415f,    //  DEC_HI[1] =  DEC_LO[6]
    -0.23037781330885523f    //  DEC_HI[0] = -DEC_LO[7]
};

__global__ __launch_bounds__(256) void WaveletTransform_23244363006050_kernel(
        const float* __restrict__ x, float* __restrict__ out) {
    const int t = blockIdx.x * 256 + threadIdx.x;
    const int b = blockIdx.y;
    if (t >= NOUT) return;

    const float* __restrict__ xr = x + (size_t)b * NN;
    const int s0 = 2 * t - 6;   // leftmost input index needed

    float v0, v1, v2, v3, v4, v5, v6, v7;
    if (t >= 3 && t <= NOUT - 4) {
        // interior: s0 >= 0, s0+7 <= N-1; s0 is even -> 8B aligned float2 loads,
        // contiguous across the wave (stride 8B per lane per instruction)
        const float2* __restrict__ p = (const float2*)(xr + s0);
        float2 a0 = p[0];
        float2 a1 = p[1];
        float2 a2 = p[2];
        float2 a3 = p[3];
        v0 = a0.x; v1 = a0.y; v2 = a1.x; v3 = a1.y;
        v4 = a2.x; v5 = a2.y; v6 = a3.x; v7 = a3.y;
    } else {
        // boundary: symmetric reflection (only t in {0,1,2, 8192,8193,8194})
        float tmp[8];
        #pragma unroll
        for (int j = 0; j < 8; ++j) {
            int s = s0 + j;
            int idx = (s < 0) ? (-s - 1) : ((s >= NN) ? (2 * NN - 1 - s) : s);
            tmp[j] = xr[idx];
        }
        v0 = tmp[0]; v1 = tmp[1]; v2 = tmp[2]; v3 = tmp[3];
        v4 = tmp[4]; v5 = tmp[5]; v6 = tmp[6]; v7 = tmp[7];
    }

    float cA = 0.0f, cD = 0.0f;
    cA = fmaf(v0, LO_R[0], cA);  cD = fmaf(v0, HI_R[0], cD);
    cA = fmaf(v1, LO_R[1], cA);  cD = fmaf(v1, HI_R[1], cD);
    cA = fmaf(v2, LO_R[2], cA);  cD = fmaf(v2, HI_R[2], cD);
    cA = fmaf(v3, LO_R[3], cA);  cD = fmaf(v3, HI_R[3], cD);
    cA = fmaf(v4, LO_R[4], cA);  cD = fmaf(v4, HI_R[4], cD);
    cA = fmaf(v5, LO_R[5], cA);  cD = fmaf(v5, HI_R[5], cD);
    cA = fmaf(v6, LO_R[6], cA);  cD = fmaf(v6, HI_R[6], cD);
    cA = fmaf(v7, LO_R[7], cA);  cD = fmaf(v7, HI_R[7], cD);

    const size_t ob = (size_t)b * OUTROW + t;
    out[ob]        = cA;   // cA stream: coalesced across t
    out[ob + NOUT] = cD;   // cD stream: coalesced across t
}

extern "C" void kernel_launch(void* const* d_in, const int* in_sizes, int n_in,
                              void* d_out, int out_size, void* d_ws, size_t ws_size,
                              hipStream_t stream) {
    const float* x = (const float*)d_in[0];
    float* out = (float*)d_out;
    dim3 grid((NOUT + 255) / 256, BB);
    WaveletTransform_23244363006050_kernel<<<grid, dim3(256), 0, stream>>>(x, out);
}

// Round 2
// 423.833 us; speedup vs baseline: 1.2850x; 1.2850x over previous
//
#include <hip/hip_runtime.h>

// db4 DWT, one level, symmetric padding.
//   cA[t] = sum_m DEC_LO[7-m] * x_sym(2t-6+m),  t in [0, 8195)
//   x_sym(s) = x[-s-1] (s<0), x[s] (0<=s<N), x[2N-1-s] (s>=N)
// out row layout: [cA (8195) | cD (8195)]
//
// Block = 256 threads, processes 1024 outputs of one row (last x-block: 1027).
// Phase 1: stage input tile (float4 global loads, 16B aligned) into LDS with a
//          +4-per-32 pad so the stride-8 compute reads don't 16-way conflict.
// Phase 2: 4 outputs/thread from LDS (4x ds_read_b128), 64 FMAs.
// Phase 3: restage cA/cD to LDS (float4 writes).
// Phase 4: aligned float4 global stores with scalar head/tail to absorb the
//          per-row misalignment (row base 16390 floats ≡ 2 mod 4; +8195 odd).

#define BB      4096
#define NN      16384
#define NOUT    8195
#define OUTROW  16390
#define TOUT_BLK 1024
#define GRIDX   8
#define SPAN_ALLOC 2072            // staged floats per block (mult of 4)
#define NLOAD4  (SPAN_ALLOC / 4)   // 518
#define LDS_IN_SZ 2328             // ldsidx(2071)+1 = 2327+1
#define CAP     1032               // >= 1028 outputs staged (last block)

__device__ __forceinline__ int ldsidx(int o) { return o + ((o >> 5) << 2); }

__global__ __launch_bounds__(256) void WaveletTransform_23244363006050_kernel(
        const float* __restrict__ x, float* __restrict__ out) {
    __shared__ float in_s[LDS_IN_SZ];
    __shared__ float cA_s[CAP];
    __shared__ float cD_s[CAP];

    const int tid = threadIdx.x;
    const int bx  = blockIdx.x;
    const int b   = blockIdx.y;
    const int t0  = bx * TOUT_BLK;
    const int touts = (bx == GRIDX - 1) ? (NOUT - t0) : TOUT_BLK;  // 1024 or 1027
    const float* __restrict__ xr = x + (size_t)b * NN;
    const int s_lo = 2 * t0 - 8;   // first staged input index (16B aligned)

    // ---- Phase 1: global -> LDS ----
    for (int k = tid; k < NLOAD4; k += 256) {
        const int o = 4 * k;
        const int s = s_lo + o;
        float4 v;
        if (s >= 0 && s + 3 < NN) {
            v = *(const float4*)(xr + s);
        } else {
            float tmp[4];
            #pragma unroll
            for (int j = 0; j < 4; ++j) {
                int ss = s + j;
                int idx = (ss < 0) ? (-ss - 1) : ((ss >= NN) ? (2 * NN - 1 - ss) : ss);
                tmp[j] = xr[idx];
            }
            v = make_float4(tmp[0], tmp[1], tmp[2], tmp[3]);
        }
        *(float4*)&in_s[ldsidx(o)] = v;
    }
    __syncthreads();

    // ---- Phase 2+3: compute 4 outputs per quad, stage results ----
    const float LO[8] = {  0.23037781330885523f,  0.7148465705525415f,
                           0.6308807679295904f,  -0.02798376941698385f,
                          -0.18703481171888114f,  0.030841381835986965f,
                           0.032883011666982945f,-0.010597401784997278f };
    const float HI[8] = { -0.010597401784997278f,-0.032883011666982945f,
                           0.030841381835986965f, 0.18703481171888114f,
                          -0.02798376941698385f, -0.6308807679295904f,
                           0.7148465705525415f,  -0.23037781330885523f };

    for (int q = tid; 4 * q < touts; q += 256) {
        const int O = 8 * q;                 // output j uses v[2j+2 .. 2j+9]
        float4 a0 = *(const float4*)&in_s[ldsidx(O)];
        float4 a1 = *(const float4*)&in_s[ldsidx(O + 4)];
        float4 a2 = *(const float4*)&in_s[ldsidx(O + 8)];
        float4 a3 = *(const float4*)&in_s[ldsidx(O + 12)];
        float v[16] = { a0.x,a0.y,a0.z,a0.w, a1.x,a1.y,a1.z,a1.w,
                        a2.x,a2.y,a2.z,a2.w, a3.x,a3.y,a3.z,a3.w };
        float accA[4], accD[4];
        #pragma unroll
        for (int j = 0; j < 4; ++j) {
            float a = 0.f, d = 0.f;
            #pragma unroll
            for (int m = 0; m < 8; ++m) {
                float vv = v[2 * j + 2 + m];
                a = fmaf(vv, LO[m], a);
                d = fmaf(vv, HI[m], d);
            }
            accA[j] = a; accD[j] = d;
        }
        *(float4*)&cA_s[4 * q] = make_float4(accA[0], accA[1], accA[2], accA[3]);
        *(float4*)&cD_s[4 * q] = make_float4(accD[0], accD[1], accD[2], accD[3]);
    }
    __syncthreads();

    // ---- Phase 4: LDS -> global, 16B-aligned stores ----
    const size_t rb = (size_t)b * OUTROW;
    {   // cA stream; (g0 & 3) is even -> h in {0, 2}
        const size_t g0 = rb + t0;
        const int h = (int)((4 - (g0 & 3)) & 3);
        const int nv = (touts - h) >> 2;
        const int tail = touts - h - (nv << 2);
        if (tid < h) out[g0 + tid] = cA_s[tid];
        for (int k = tid; k < nv; k += 256) {
            const int lo = h + 4 * k;
            float2 p0 = *(const float2*)&cA_s[lo];
            float2 p1 = *(const float2*)&cA_s[lo + 2];
            *(float4*)(out + g0 + lo) = make_float4(p0.x, p0.y, p1.x, p1.y);
        }
        if (tid < tail) { const int lo = h + (nv << 2) + tid; out[g0 + lo] = cA_s[lo]; }
    }
    {   // cD stream; (g0 & 3) is odd -> h in {1, 3}
        const size_t g0 = rb + NOUT + t0;
        const int h = (int)((4 - (g0 & 3)) & 3);
        const int nv = (touts - h) >> 2;
        const int tail = touts - h - (nv << 2);
        if (tid < h) out[g0 + tid] = cD_s[tid];
        for (int k = tid; k < nv; k += 256) {
            const int lo = h + 4 * k;
            *(float4*)(out + g0 + lo) =
                make_float4(cD_s[lo], cD_s[lo + 1], cD_s[lo + 2], cD_s[lo + 3]);
        }
        if (tid < tail) { const int lo = h + (nv << 2) + tid; out[g0 + lo] = cD_s[lo]; }
    }
}

extern "C" void kernel_launch(void* const* d_in, const int* in_sizes, int n_in,
                              void* d_out, int out_size, void* d_ws, size_t ws_size,
                              hipStream_t stream) {
    const float* x = (const float*)d_in[0];
    float* out = (float*)d_out;
    dim3 grid(GRIDX, BB);
    WaveletTransform_23244363006050_kernel<<<grid, dim3(256), 0, stream>>>(x, out);
}